// Round 14
// baseline (49.586 us; speedup 1.0000x reference)
//
#include <hip/hip_runtime.h>

#define B_ 8
#define N_ 256
#define D_ 512

// async 16B global -> LDS. FULL-WAVE ONLY (exec-masked LDS-DMA corrupts LDS).
__device__ __forceinline__ void load_lds_16B(const float* g, float* l)
{
    __builtin_amdgcn_global_load_lds(
        (const __attribute__((address_space(1))) void*)g,
        (__attribute__((address_space(3))) void*)l, 16, 0, 0);
}

// ================= Kernel A: scores S[b][i][j] = -sum_d |q-k| =============
// grid 1024: b=bid&7, itile=(bid>>3)&31 -> 8 rows, jq=bid>>8 -> 64 j.
// 256 thr, wave w = (parity p = w>>1) x (row-group rg = w&1 -> 4 rows).
// Each wave reads only its parity's d-quads (dgi = 2i+p) -> k LDS reads
// halved vs R12 (2 waves share each quad, not 4); rows/thread 2->4.
// Staging + swizzle byte-identical to R12-verified scheme.
__global__ __launch_bounds__(256)
void manh_scores2(const float* __restrict__ q,
                  const float* __restrict__ k,
                  float* __restrict__ S)
{
    __shared__ __align__(16) float s_k[2][4096];   // 32 KB: 64-d chunk dbuf
    __shared__ __align__(16) float s_red[1024];    // 4 KB: 4 waves x 4 rows x 64 j

    const int t     = threadIdx.x;
    const int b     = blockIdx.x & 7;          // batch -> XCD locality
    const int itile = (blockIdx.x >> 3) & 31;
    const int jq    = blockIdx.x >> 8;         // 0..3
    const int ibase = itile * 8;
    const int jbase = jq * 64;

    const float* __restrict__ kb = k + (size_t)b * N_ * D_;

    const int dg = (t & 3) ^ ((t >> 3) & 3);
    const float* ksrc = kb + (size_t)(jbase + (t >> 2)) * D_ + dg * 4;

#define STAGEA(cc, sb)                                              \
    {                                                               \
        load_lds_16B(ksrc + (cc) * 64,      &s_k[sb][4 * t]);       \
        load_lds_16B(ksrc + (cc) * 64 + 16, &s_k[sb][1024 + 4 * t]);\
        load_lds_16B(ksrc + (cc) * 64 + 32, &s_k[sb][2048 + 4 * t]);\
        load_lds_16B(ksrc + (cc) * 64 + 48, &s_k[sb][3072 + 4 * t]);\
    }

    STAGEA(0, 0)
    __syncthreads();

    const int w     = t >> 6;
    const int j     = t & 63;
    const int p     = (w >> 1) & 1;                 // d-quad parity
    const int rbase = __builtin_amdgcn_readfirstlane((w & 1) * 4);
    const int swz4  = ((j >> 1) & 3) << 2;
    const float* __restrict__ qrow = q + ((size_t)(b * N_ + ibase + rbase)) * D_;

    float acc0 = 0.f, acc1 = 0.f, acc2 = 0.f, acc3 = 0.f;

    int buf = 0;
    for (int c = 0; c < 8; ++c) {
        if (c < 7) STAGEA(c + 1, buf ^ 1)

        const float* kcb = &s_k[buf][0];
        #pragma unroll
        for (int i = 0; i < 8; ++i) {
            const int dgi = 2 * i + p;             // this wave's parity only
            const float4 k4 = *(const float4*)
                (kcb + (dgi >> 2) * 1024 + (j << 4) + (((dgi & 3) << 2) ^ swz4));
            const int doff = c * 64 + dgi * 4;
            const float4 q0 = *(const float4*)(qrow + doff);
            const float4 q1 = *(const float4*)(qrow + D_ + doff);
            const float4 q2 = *(const float4*)(qrow + 2 * D_ + doff);
            const float4 q3 = *(const float4*)(qrow + 3 * D_ + doff);
            acc0 += (fabsf(q0.x - k4.x) + fabsf(q0.y - k4.y)) +
                    (fabsf(q0.z - k4.z) + fabsf(q0.w - k4.w));
            acc1 += (fabsf(q1.x - k4.x) + fabsf(q1.y - k4.y)) +
                    (fabsf(q1.z - k4.z) + fabsf(q1.w - k4.w));
            acc2 += (fabsf(q2.x - k4.x) + fabsf(q2.y - k4.y)) +
                    (fabsf(q2.z - k4.z) + fabsf(q2.w - k4.w));
            acc3 += (fabsf(q3.x - k4.x) + fabsf(q3.y - k4.y)) +
                    (fabsf(q3.z - k4.z) + fabsf(q3.w - k4.w));
        }

        __syncthreads();
        buf ^= 1;
    }
#undef STAGEA

    // ---- combine the 2 parity partials per row ----
    s_red[w * 256 +   0 + j] = acc0;
    s_red[w * 256 +  64 + j] = acc1;
    s_red[w * 256 + 128 + j] = acc2;
    s_red[w * 256 + 192 + j] = acc3;
    __syncthreads();

    #pragma unroll
    for (int e = t; e < 512; e += 256) {
        const int r  = e >> 6;                     // 0..7
        const int jj = e & 63;
        const int rg = r >> 2;                     // row-group 0..1
        const int rl = r & 3;
        // waves rg (p=0) and rg+2 (p=1) hold row r's partials
        const float sum = s_red[rg * 256 + rl * 64 + jj] +
                          s_red[(rg + 2) * 256 + rl * 64 + jj];
        S[(size_t)b * N_ * N_ + (size_t)(ibase + r) * N_ + jbase + jj] = -sum;
    }
}

// ================= Kernel B: softmax(S) @ v, 8 rows/block (verified R13) ===
__global__ __launch_bounds__(512, 4)
void manh_sm_pv8(const float* __restrict__ S,
                 const float* __restrict__ v,
                 float* __restrict__ out)
{
    __shared__ __align__(16) float s_w[8 * N_];      // 8 KB
    __shared__ __align__(16) float s_part[8 * 1024]; // 32 KB

    const int t     = threadIdx.x;
    const int lane  = t & 63;
    const int w     = t >> 6;              // 0..7
    const int b     = blockIdx.x & 7;
    const int itile = (blockIdx.x >> 3) & 31;
    const int dh    = blockIdx.x >> 8;     // 0..1
    const int i0    = itile * 8;

    *(float4*)&s_w[4 * t] =
        *(const float4*)(S + (size_t)b * N_ * N_ + (size_t)i0 * N_ + 4 * t);
    __syncthreads();

    {
        float* row = &s_w[w * N_];
        float v0 = row[lane];
        float v1 = row[lane + 64];
        float v2 = row[lane + 128];
        float v3 = row[lane + 192];
        float m = fmaxf(fmaxf(v0, v1), fmaxf(v2, v3));
        #pragma unroll
        for (int off = 32; off; off >>= 1) m = fmaxf(m, __shfl_xor(m, off));
        const float cc = 1.4426950408889634f;
        float e0 = exp2f((v0 - m) * cc);
        float e1 = exp2f((v1 - m) * cc);
        float e2 = exp2f((v2 - m) * cc);
        float e3 = exp2f((v3 - m) * cc);
        float s = (e0 + e1) + (e2 + e3);
        #pragma unroll
        for (int off = 32; off; off >>= 1) s += __shfl_xor(s, off);
        const float r = 1.0f / s;
        row[lane]       = e0 * r;
        row[lane + 64]  = e1 * r;
        row[lane + 128] = e2 * r;
        row[lane + 192] = e3 * r;
    }
    __syncthreads();

    const int dq    = t & 63;
    const int jh    = t >> 6;              // == wave -> s_w reads wave-uniform
    const int dbase = dh * 256 + dq * 4;
    const float* __restrict__ vb = v + (size_t)b * N_ * D_ + dbase;

    float4 a0 = make_float4(0.f,0.f,0.f,0.f), a1 = a0, a2 = a0, a3 = a0;
    float4 a4 = a0, a5 = a0, a6 = a0, a7 = a0;

#define PVROW(A, W)                                                            \
    A.x += (W).x * vv0.x + (W).y * vv1.x + (W).z * vv2.x + (W).w * vv3.x;      \
    A.y += (W).x * vv0.y + (W).y * vv1.y + (W).z * vv2.y + (W).w * vv3.y;      \
    A.z += (W).x * vv0.z + (W).y * vv1.z + (W).z * vv2.z + (W).w * vv3.z;      \
    A.w += (W).x * vv0.w + (W).y * vv1.w + (W).z * vv2.w + (W).w * vv3.w;

    #pragma unroll 2
    for (int jo = 0; jo < 32; jo += 4) {
        const int jj = jh * 32 + jo;
        const float4 vv0 = *(const float4*)(vb + (size_t)(jj + 0) * D_);
        const float4 vv1 = *(const float4*)(vb + (size_t)(jj + 1) * D_);
        const float4 vv2 = *(const float4*)(vb + (size_t)(jj + 2) * D_);
        const float4 vv3 = *(const float4*)(vb + (size_t)(jj + 3) * D_);
        const float4 w0 = *(const float4*)&s_w[0 * N_ + jj];
        const float4 w1 = *(const float4*)&s_w[1 * N_ + jj];
        const float4 w2 = *(const float4*)&s_w[2 * N_ + jj];
        const float4 w3 = *(const float4*)&s_w[3 * N_ + jj];
        const float4 w4 = *(const float4*)&s_w[4 * N_ + jj];
        const float4 w5 = *(const float4*)&s_w[5 * N_ + jj];
        const float4 w6 = *(const float4*)&s_w[6 * N_ + jj];
        const float4 w7 = *(const float4*)&s_w[7 * N_ + jj];
        PVROW(a0, w0) PVROW(a1, w1) PVROW(a2, w2) PVROW(a3, w3)
        PVROW(a4, w4) PVROW(a5, w5) PVROW(a6, w6) PVROW(a7, w7)
    }
#undef PVROW

    *(float4*)&s_part[jh * 1024 + 0 * 256 + dq * 4] = a0;
    *(float4*)&s_part[jh * 1024 + 1 * 256 + dq * 4] = a1;
    *(float4*)&s_part[jh * 1024 + 2 * 256 + dq * 4] = a2;
    *(float4*)&s_part[jh * 1024 + 3 * 256 + dq * 4] = a3;
    __syncthreads();
    if (t < 256) {
        const int r  = t >> 6;
        const int d4 = (t & 63) * 4;
        float4 s = make_float4(0.f,0.f,0.f,0.f);
        #pragma unroll
        for (int g = 0; g < 8; ++g) {
            const float4 p = *(const float4*)&s_part[g * 1024 + r * 256 + d4];
            s.x += p.x; s.y += p.y; s.z += p.z; s.w += p.w;
        }
        *(float4*)(out + ((size_t)(b * N_ + i0 + r)) * D_ + dh * 256 + d4) = s;
    }
    __syncthreads();
    *(float4*)&s_part[jh * 1024 + 0 * 256 + dq * 4] = a4;
    *(float4*)&s_part[jh * 1024 + 1 * 256 + dq * 4] = a5;
    *(float4*)&s_part[jh * 1024 + 2 * 256 + dq * 4] = a6;
    *(float4*)&s_part[jh * 1024 + 3 * 256 + dq * 4] = a7;
    __syncthreads();
    if (t < 256) {
        const int r  = t >> 6;
        const int d4 = (t & 63) * 4;
        float4 s = make_float4(0.f,0.f,0.f,0.f);
        #pragma unroll
        for (int g = 0; g < 8; ++g) {
            const float4 p = *(const float4*)&s_part[g * 1024 + r * 256 + d4];
            s.x += p.x; s.y += p.y; s.z += p.z; s.w += p.w;
        }
        *(float4*)(out + ((size_t)(b * N_ + i0 + 4 + r)) * D_ + dh * 256 + d4) = s;
    }
}

// ---------- Fallback (round-1 kernel) if ws can't hold S (2 MB) ----------
__global__ __launch_bounds__(256, 2)
void manh_attn_legacy(const float* __restrict__ q,
                      const float* __restrict__ k,
                      const float* __restrict__ v,
                      float* __restrict__ out)
{
    __shared__ float s_mat[4][N_];
    const int t   = threadIdx.x;
    const int bid = blockIdx.x;
    const int b   = bid >> 6;
    const int i0  = (bid & 63) * 4;

    const float* __restrict__ krow  = k + ((size_t)(b * N_ + t)) * D_;
    const float* __restrict__ qbase = q + ((size_t)(b * N_ + i0)) * D_;

    float acc0 = 0.f, acc1 = 0.f, acc2 = 0.f, acc3 = 0.f;
    #pragma unroll 4
    for (int d = 0; d < D_; d += 4) {
        const float4 kv = *(const float4*)(krow + d);
        const float4 q0 = *(const float4*)(qbase + d);
        const float4 q1 = *(const float4*)(qbase + D_ + d);
        const float4 q2 = *(const float4*)(qbase + 2 * D_ + d);
        const float4 q3 = *(const float4*)(qbase + 3 * D_ + d);
        acc0 += (fabsf(q0.x - kv.x) + fabsf(q0.y - kv.y)) + (fabsf(q0.z - kv.z) + fabsf(q0.w - kv.w));
        acc1 += (fabsf(q1.x - kv.x) + fabsf(q1.y - kv.y)) + (fabsf(q1.z - kv.z) + fabsf(q1.w - kv.w));
        acc2 += (fabsf(q2.x - kv.x) + fabsf(q2.y - kv.y)) + (fabsf(q2.z - kv.z) + fabsf(q2.w - kv.w));
        acc3 += (fabsf(q3.x - kv.x) + fabsf(q3.y - kv.y)) + (fabsf(q3.z - kv.z) + fabsf(q3.w - kv.w));
    }
    s_mat[0][t] = -acc0; s_mat[1][t] = -acc1; s_mat[2][t] = -acc2; s_mat[3][t] = -acc3;
    __syncthreads();
    {
        const int w = t >> 6;
        const int l = t & 63;
        float v0 = s_mat[w][l], v1 = s_mat[w][l + 64], v2 = s_mat[w][l + 128], v3 = s_mat[w][l + 192];
        float m = fmaxf(fmaxf(v0, v1), fmaxf(v2, v3));
        #pragma unroll
        for (int off = 32; off; off >>= 1) m = fmaxf(m, __shfl_xor(m, off));
        const float c = 1.4426950408889634f;
        float e0 = exp2f((v0 - m) * c), e1 = exp2f((v1 - m) * c);
        float e2 = exp2f((v2 - m) * c), e3 = exp2f((v3 - m) * c);
        float s = (e0 + e1) + (e2 + e3);
        #pragma unroll
        for (int off = 32; off; off >>= 1) s += __shfl_xor(s, off);
        const float r = 1.0f / s;
        s_mat[w][l] = e0 * r; s_mat[w][l + 64] = e1 * r;
        s_mat[w][l + 128] = e2 * r; s_mat[w][l + 192] = e3 * r;
    }
    __syncthreads();
    const int ig = t >> 7;
    const int d0 = (t & 127) * 4;
    const float* __restrict__ vbase = v + ((size_t)b * N_) * D_ + d0;
    const float* __restrict__ wr0 = &s_mat[2 * ig][0];
    const float* __restrict__ wr1 = &s_mat[2 * ig + 1][0];
    float4 a0 = make_float4(0.f, 0.f, 0.f, 0.f);
    float4 a1 = make_float4(0.f, 0.f, 0.f, 0.f);
#define PV_STEP(W0, W1, VV)                                     \
    a0.x += (W0) * (VV).x; a0.y += (W0) * (VV).y;               \
    a0.z += (W0) * (VV).z; a0.w += (W0) * (VV).w;               \
    a1.x += (W1) * (VV).x; a1.y += (W1) * (VV).y;               \
    a1.z += (W1) * (VV).z; a1.w += (W1) * (VV).w;
    #pragma unroll 2
    for (int j = 0; j < N_; j += 4) {
        const float4 w0 = *(const float4*)(wr0 + j);
        const float4 w1 = *(const float4*)(wr1 + j);
        const float4 vv0 = *(const float4*)(vbase + (size_t)(j + 0) * D_);
        const float4 vv1 = *(const float4*)(vbase + (size_t)(j + 1) * D_);
        const float4 vv2 = *(const float4*)(vbase + (size_t)(j + 2) * D_);
        const float4 vv3 = *(const float4*)(vbase + (size_t)(j + 3) * D_);
        PV_STEP(w0.x, w1.x, vv0)
        PV_STEP(w0.y, w1.y, vv1)
        PV_STEP(w0.z, w1.z, vv2)
        PV_STEP(w0.w, w1.w, vv3)
    }
#undef PV_STEP
    float* op = out + ((size_t)(b * N_ + i0 + 2 * ig)) * D_ + d0;
    *(float4*)op        = a0;
    *(float4*)(op + D_) = a1;
}

extern "C" void kernel_launch(void* const* d_in, const int* in_sizes, int n_in,
                              void* d_out, int out_size, void* d_ws, size_t ws_size,
                              hipStream_t stream)
{
    const float* q = (const float*)d_in[0];
    const float* k = (const float*)d_in[1];
    const float* v = (const float*)d_in[2];
    float* out = (float*)d_out;

    const size_t S_bytes = (size_t)B_ * N_ * N_ * sizeof(float);
    if (ws_size >= S_bytes) {
        float* S = (float*)d_ws;
        manh_scores2<<<dim3(1024), dim3(256), 0, stream>>>(q, k, S);
        manh_sm_pv8<<<dim3(512), dim3(512), 0, stream>>>(S, v, out);
    } else {
        manh_attn_legacy<<<dim3(B_ * 64), dim3(256), 0, stream>>>(q, k, v, out);
    }
}

// Round 15
// 37.632 us; speedup vs baseline: 1.3177x; 1.3177x over previous
//
#include <hip/hip_runtime.h>

#define B_ 8
#define N_ 256
#define D_ 512

// async 16B global -> LDS. FULL-WAVE ONLY (exec-masked LDS-DMA corrupts LDS).
__device__ __forceinline__ void load_lds_16B(const float* g, float* l)
{
    __builtin_amdgcn_global_load_lds(
        (const __attribute__((address_space(1))) void*)g,
        (__attribute__((address_space(3))) void*)l, 16, 0, 0);
}

// ================= Kernel A: scores S[b][i][j] = -sum_d |q-k| =============
// grid 1024: b=bid&7, itile=(bid>>3)&31 -> 8 rows, jq=bid>>8 -> 64 j.
// 256 thr. Wave w owns the CONTIGUOUS d-quarter dgi in [4w,4w+4) of each
// 64-d chunk, for ALL 8 rows (8 scalar accs). vs R12: 4x fewer k ds_reads,
// same VALU, q scalar loads stay contiguous/mergeable (R14's stride-2
// parity split broke s_load merging + forced lgkmcnt(0) drains).
// Staging + swizzle byte-identical to R12-verified scheme.
__global__ __launch_bounds__(256)
void manh_scores3(const float* __restrict__ q,
                  const float* __restrict__ k,
                  float* __restrict__ S)
{
    __shared__ __align__(16) float s_k[2][4096];   // 32 KB: 64-d chunk dbuf
    __shared__ __align__(16) float s_red[2048];    // 8 KB: 4 waves x 8 rows x 64 j

    const int t     = threadIdx.x;
    const int b     = blockIdx.x & 7;          // batch -> XCD locality
    const int itile = (blockIdx.x >> 3) & 31;
    const int jq    = blockIdx.x >> 8;         // 0..3
    const int ibase = itile * 8;
    const int jbase = jq * 64;

    const float* __restrict__ kb = k + (size_t)b * N_ * D_;

    const int dg = (t & 3) ^ ((t >> 3) & 3);
    const float* ksrc = kb + (size_t)(jbase + (t >> 2)) * D_ + dg * 4;

#define STAGEA(cc, sb)                                              \
    {                                                               \
        load_lds_16B(ksrc + (cc) * 64,      &s_k[sb][4 * t]);       \
        load_lds_16B(ksrc + (cc) * 64 + 16, &s_k[sb][1024 + 4 * t]);\
        load_lds_16B(ksrc + (cc) * 64 + 32, &s_k[sb][2048 + 4 * t]);\
        load_lds_16B(ksrc + (cc) * 64 + 48, &s_k[sb][3072 + 4 * t]);\
    }

    STAGEA(0, 0)
    __syncthreads();

    const int w    = t >> 6;                   // wave = d-quarter of chunk
    const int j    = t & 63;
    const int swz  = (j >> 1) & 3;
    const int dlo  = __builtin_amdgcn_readfirstlane(w * 16); // chunk-local d base
    const float* __restrict__ qrow = q + ((size_t)(b * N_ + ibase)) * D_;

    float a0 = 0.f, a1 = 0.f, a2 = 0.f, a3 = 0.f;
    float a4 = 0.f, a5 = 0.f, a6 = 0.f, a7 = 0.f;

    int buf = 0;
    for (int c = 0; c < 8; ++c) {
        if (c < 7) STAGEA(c + 1, buf ^ 1)

        const float* kcb = &s_k[buf][w * 1024 + (j << 4)];
        const int dbase = c * 64 + dlo;        // 16 contiguous d for this wave
        #pragma unroll
        for (int i = 0; i < 4; ++i) {
            const float4 k4 = *(const float4*)(kcb + ((i ^ swz) << 2));
            const int doff = dbase + i * 4;
#define ACCR(A, R)                                                             \
            {                                                                  \
                const float4 q4 = *(const float4*)(qrow + (size_t)(R) * D_ + doff); \
                A += (fabsf(q4.x - k4.x) + fabsf(q4.y - k4.y)) +               \
                     (fabsf(q4.z - k4.z) + fabsf(q4.w - k4.w));                \
            }
            ACCR(a0, 0) ACCR(a1, 1) ACCR(a2, 2) ACCR(a3, 3)
            ACCR(a4, 4) ACCR(a5, 5) ACCR(a6, 6) ACCR(a7, 7)
#undef ACCR
        }

        __syncthreads();
        buf ^= 1;
    }
#undef STAGEA

    // ---- dump 8 row-partials (one shot), reduce 4 d-quarters ----
    s_red[w * 512 + 0 * 64 + j] = a0;
    s_red[w * 512 + 1 * 64 + j] = a1;
    s_red[w * 512 + 2 * 64 + j] = a2;
    s_red[w * 512 + 3 * 64 + j] = a3;
    // second half interleaved via barrier-free different addresses
    __syncthreads();   // ensure no reader races ahead (s_red half 1 writes next)
    s_red[w * 512 + 4 * 64 + j] = a4;
    s_red[w * 512 + 5 * 64 + j] = a5;
    s_red[w * 512 + 6 * 64 + j] = a6;
    s_red[w * 512 + 7 * 64 + j] = a7;
    __syncthreads();

    #pragma unroll
    for (int e = t; e < 512; e += 256) {
        const int r  = e >> 6;                 // 0..7
        const int jj = e & 63;
        const int sl = r * 64 + jj;
        const float sum = (s_red[0 * 512 + sl] + s_red[1 * 512 + sl]) +
                          (s_red[2 * 512 + sl] + s_red[3 * 512 + sl]);
        S[(size_t)b * N_ * N_ + (size_t)(ibase + r) * N_ + jbase + jj] = -sum;
    }
}

// ================= Kernel B: softmax(S) @ v, 8 rows/block (verified R13) ===
__global__ __launch_bounds__(512, 4)
void manh_sm_pv8(const float* __restrict__ S,
                 const float* __restrict__ v,
                 float* __restrict__ out)
{
    __shared__ __align__(16) float s_w[8 * N_];      // 8 KB
    __shared__ __align__(16) float s_part[8 * 1024]; // 32 KB

    const int t     = threadIdx.x;
    const int lane  = t & 63;
    const int w     = t >> 6;              // 0..7
    const int b     = blockIdx.x & 7;
    const int itile = (blockIdx.x >> 3) & 31;
    const int dh    = blockIdx.x >> 8;     // 0..1
    const int i0    = itile * 8;

    *(float4*)&s_w[4 * t] =
        *(const float4*)(S + (size_t)b * N_ * N_ + (size_t)i0 * N_ + 4 * t);
    __syncthreads();

    {
        float* row = &s_w[w * N_];
        float v0 = row[lane];
        float v1 = row[lane + 64];
        float v2 = row[lane + 128];
        float v3 = row[lane + 192];
        float m = fmaxf(fmaxf(v0, v1), fmaxf(v2, v3));
        #pragma unroll
        for (int off = 32; off; off >>= 1) m = fmaxf(m, __shfl_xor(m, off));
        const float cc = 1.4426950408889634f;
        float e0 = exp2f((v0 - m) * cc);
        float e1 = exp2f((v1 - m) * cc);
        float e2 = exp2f((v2 - m) * cc);
        float e3 = exp2f((v3 - m) * cc);
        float s = (e0 + e1) + (e2 + e3);
        #pragma unroll
        for (int off = 32; off; off >>= 1) s += __shfl_xor(s, off);
        const float r = 1.0f / s;
        row[lane]       = e0 * r;
        row[lane + 64]  = e1 * r;
        row[lane + 128] = e2 * r;
        row[lane + 192] = e3 * r;
    }
    __syncthreads();

    const int dq    = t & 63;
    const int jh    = t >> 6;              // == wave -> s_w reads wave-uniform
    const int dbase = dh * 256 + dq * 4;
    const float* __restrict__ vb = v + (size_t)b * N_ * D_ + dbase;

    float4 a0 = make_float4(0.f,0.f,0.f,0.f), a1 = a0, a2 = a0, a3 = a0;
    float4 a4 = a0, a5 = a0, a6 = a0, a7 = a0;

#define PVROW(A, W)                                                            \
    A.x += (W).x * vv0.x + (W).y * vv1.x + (W).z * vv2.x + (W).w * vv3.x;      \
    A.y += (W).x * vv0.y + (W).y * vv1.y + (W).z * vv2.y + (W).w * vv3.y;      \
    A.z += (W).x * vv0.z + (W).y * vv1.z + (W).z * vv2.z + (W).w * vv3.z;      \
    A.w += (W).x * vv0.w + (W).y * vv1.w + (W).z * vv2.w + (W).w * vv3.w;

    #pragma unroll 2
    for (int jo = 0; jo < 32; jo += 4) {
        const int jj = jh * 32 + jo;
        const float4 vv0 = *(const float4*)(vb + (size_t)(jj + 0) * D_);
        const float4 vv1 = *(const float4*)(vb + (size_t)(jj + 1) * D_);
        const float4 vv2 = *(const float4*)(vb + (size_t)(jj + 2) * D_);
        const float4 vv3 = *(const float4*)(vb + (size_t)(jj + 3) * D_);
        const float4 w0 = *(const float4*)&s_w[0 * N_ + jj];
        const float4 w1 = *(const float4*)&s_w[1 * N_ + jj];
        const float4 w2 = *(const float4*)&s_w[2 * N_ + jj];
        const float4 w3 = *(const float4*)&s_w[3 * N_ + jj];
        const float4 w4 = *(const float4*)&s_w[4 * N_ + jj];
        const float4 w5 = *(const float4*)&s_w[5 * N_ + jj];
        const float4 w6 = *(const float4*)&s_w[6 * N_ + jj];
        const float4 w7 = *(const float4*)&s_w[7 * N_ + jj];
        PVROW(a0, w0) PVROW(a1, w1) PVROW(a2, w2) PVROW(a3, w3)
        PVROW(a4, w4) PVROW(a5, w5) PVROW(a6, w6) PVROW(a7, w7)
    }
#undef PVROW

    *(float4*)&s_part[jh * 1024 + 0 * 256 + dq * 4] = a0;
    *(float4*)&s_part[jh * 1024 + 1 * 256 + dq * 4] = a1;
    *(float4*)&s_part[jh * 1024 + 2 * 256 + dq * 4] = a2;
    *(float4*)&s_part[jh * 1024 + 3 * 256 + dq * 4] = a3;
    __syncthreads();
    if (t < 256) {
        const int r  = t >> 6;
        const int d4 = (t & 63) * 4;
        float4 s = make_float4(0.f,0.f,0.f,0.f);
        #pragma unroll
        for (int g = 0; g < 8; ++g) {
            const float4 p = *(const float4*)&s_part[g * 1024 + r * 256 + d4];
            s.x += p.x; s.y += p.y; s.z += p.z; s.w += p.w;
        }
        *(float4*)(out + ((size_t)(b * N_ + i0 + r)) * D_ + dh * 256 + d4) = s;
    }
    __syncthreads();
    *(float4*)&s_part[jh * 1024 + 0 * 256 + dq * 4] = a4;
    *(float4*)&s_part[jh * 1024 + 1 * 256 + dq * 4] = a5;
    *(float4*)&s_part[jh * 1024 + 2 * 256 + dq * 4] = a6;
    *(float4*)&s_part[jh * 1024 + 3 * 256 + dq * 4] = a7;
    __syncthreads();
    if (t < 256) {
        const int r  = t >> 6;
        const int d4 = (t & 63) * 4;
        float4 s = make_float4(0.f,0.f,0.f,0.f);
        #pragma unroll
        for (int g = 0; g < 8; ++g) {
            const float4 p = *(const float4*)&s_part[g * 1024 + r * 256 + d4];
            s.x += p.x; s.y += p.y; s.z += p.z; s.w += p.w;
        }
        *(float4*)(out + ((size_t)(b * N_ + i0 + 4 + r)) * D_ + dh * 256 + d4) = s;
    }
}

// ---------- Fallback (round-1 kernel) if ws can't hold S (2 MB) ----------
__global__ __launch_bounds__(256, 2)
void manh_attn_legacy(const float* __restrict__ q,
                      const float* __restrict__ k,
                      const float* __restrict__ v,
                      float* __restrict__ out)
{
    __shared__ float s_mat[4][N_];
    const int t   = threadIdx.x;
    const int bid = blockIdx.x;
    const int b   = bid >> 6;
    const int i0  = (bid & 63) * 4;

    const float* __restrict__ krow  = k + ((size_t)(b * N_ + t)) * D_;
    const float* __restrict__ qbase = q + ((size_t)(b * N_ + i0)) * D_;

    float acc0 = 0.f, acc1 = 0.f, acc2 = 0.f, acc3 = 0.f;
    #pragma unroll 4
    for (int d = 0; d < D_; d += 4) {
        const float4 kv = *(const float4*)(krow + d);
        const float4 q0 = *(const float4*)(qbase + d);
        const float4 q1 = *(const float4*)(qbase + D_ + d);
        const float4 q2 = *(const float4*)(qbase + 2 * D_ + d);
        const float4 q3 = *(const float4*)(qbase + 3 * D_ + d);
        acc0 += (fabsf(q0.x - kv.x) + fabsf(q0.y - kv.y)) + (fabsf(q0.z - kv.z) + fabsf(q0.w - kv.w));
        acc1 += (fabsf(q1.x - kv.x) + fabsf(q1.y - kv.y)) + (fabsf(q1.z - kv.z) + fabsf(q1.w - kv.w));
        acc2 += (fabsf(q2.x - kv.x) + fabsf(q2.y - kv.y)) + (fabsf(q2.z - kv.z) + fabsf(q2.w - kv.w));
        acc3 += (fabsf(q3.x - kv.x) + fabsf(q3.y - kv.y)) + (fabsf(q3.z - kv.z) + fabsf(q3.w - kv.w));
    }
    s_mat[0][t] = -acc0; s_mat[1][t] = -acc1; s_mat[2][t] = -acc2; s_mat[3][t] = -acc3;
    __syncthreads();
    {
        const int w = t >> 6;
        const int l = t & 63;
        float v0 = s_mat[w][l], v1 = s_mat[w][l + 64], v2 = s_mat[w][l + 128], v3 = s_mat[w][l + 192];
        float m = fmaxf(fmaxf(v0, v1), fmaxf(v2, v3));
        #pragma unroll
        for (int off = 32; off; off >>= 1) m = fmaxf(m, __shfl_xor(m, off));
        const float c = 1.4426950408889634f;
        float e0 = exp2f((v0 - m) * c), e1 = exp2f((v1 - m) * c);
        float e2 = exp2f((v2 - m) * c), e3 = exp2f((v3 - m) * c);
        float s = (e0 + e1) + (e2 + e3);
        #pragma unroll
        for (int off = 32; off; off >>= 1) s += __shfl_xor(s, off);
        const float r = 1.0f / s;
        s_mat[w][l] = e0 * r; s_mat[w][l + 64] = e1 * r;
        s_mat[w][l + 128] = e2 * r; s_mat[w][l + 192] = e3 * r;
    }
    __syncthreads();
    const int ig = t >> 7;
    const int d0 = (t & 127) * 4;
    const float* __restrict__ vbase = v + ((size_t)b * N_) * D_ + d0;
    const float* __restrict__ wr0 = &s_mat[2 * ig][0];
    const float* __restrict__ wr1 = &s_mat[2 * ig + 1][0];
    float4 a0 = make_float4(0.f, 0.f, 0.f, 0.f);
    float4 a1 = make_float4(0.f, 0.f, 0.f, 0.f);
#define PV_STEP(W0, W1, VV)                                     \
    a0.x += (W0) * (VV).x; a0.y += (W0) * (VV).y;               \
    a0.z += (W0) * (VV).z; a0.w += (W0) * (VV).w;               \
    a1.x += (W1) * (VV).x; a1.y += (W1) * (VV).y;               \
    a1.z += (W1) * (VV).z; a1.w += (W1) * (VV).w;
    #pragma unroll 2
    for (int j = 0; j < N_; j += 4) {
        const float4 w0 = *(const float4*)(wr0 + j);
        const float4 w1 = *(const float4*)(wr1 + j);
        const float4 vv0 = *(const float4*)(vbase + (size_t)(j + 0) * D_);
        const float4 vv1 = *(const float4*)(vbase + (size_t)(j + 1) * D_);
        const float4 vv2 = *(const float4*)(vbase + (size_t)(j + 2) * D_);
        const float4 vv3 = *(const float4*)(vbase + (size_t)(j + 3) * D_);
        PV_STEP(w0.x, w1.x, vv0)
        PV_STEP(w0.y, w1.y, vv1)
        PV_STEP(w0.z, w1.z, vv2)
        PV_STEP(w0.w, w1.w, vv3)
    }
#undef PV_STEP
    float* op = out + ((size_t)(b * N_ + i0 + 2 * ig)) * D_ + d0;
    *(float4*)op        = a0;
    *(float4*)(op + D_) = a1;
}

extern "C" void kernel_launch(void* const* d_in, const int* in_sizes, int n_in,
                              void* d_out, int out_size, void* d_ws, size_t ws_size,
                              hipStream_t stream)
{
    const float* q = (const float*)d_in[0];
    const float* k = (const float*)d_in[1];
    const float* v = (const float*)d_in[2];
    float* out = (float*)d_out;

    const size_t S_bytes = (size_t)B_ * N_ * N_ * sizeof(float);
    if (ws_size >= S_bytes) {
        float* S = (float*)d_ws;
        manh_scores3<<<dim3(1024), dim3(256), 0, stream>>>(q, k, S);
        manh_sm_pv8<<<dim3(512), dim3(512), 0, stream>>>(S, v, out);
    } else {
        manh_attn_legacy<<<dim3(B_ * 64), dim3(256), 0, stream>>>(q, k, v, out);
    }
}